// Round 6
// baseline (662.718 us; speedup 1.0000x reference)
//
#include <hip/hip_runtime.h>
#include <stdint.h>

#define MQ 256
#define NB 50000
#define KD 2048
#define BN 64
#define BK 64
#define KT (KD / BK)
#define NBLK ((NB + BN - 1) / BN)  // 782

typedef __attribute__((ext_vector_type(8))) short bf16x8;
typedef __attribute__((ext_vector_type(4))) float f32x4;

// machine-sched + IR-level motion fence (pins the VMEM FIFO issue order)
#define SFENCE()                       \
  do {                                 \
    asm volatile("" ::: "memory");     \
    __builtin_amdgcn_sched_barrier(0); \
  } while (0)

__device__ __forceinline__ unsigned int pack_bf16(float a, float b) {
  unsigned int ua = __float_as_uint(a);
  ua += 0x7fffu + ((ua >> 16) & 1u);
  unsigned int ub = __float_as_uint(b);
  ub += 0x7fffu + ((ub >> 16) & 1u);
  return (ua >> 16) | (ub & 0xffff0000u);
}

// order-preserving float<->uint map (total order, works for negatives)
__device__ __forceinline__ unsigned int ordf(float f) {
  unsigned int u = __float_as_uint(f);
  return (u & 0x80000000u) ? ~u : (u | 0x80000000u);
}
__device__ __forceinline__ float deordf(unsigned int e) {
  unsigned int u = (e & 0x80000000u) ? (e ^ 0x80000000u) : ~e;
  return __uint_as_float(u);
}

__device__ __forceinline__ float wave_sum(float v) {
#pragma unroll
  for (int o = 32; o > 0; o >>= 1) v += __shfl_down(v, o, 64);
  return v;
}

// ---------------- kernel 1: queries fp32 -> bf16 (+ q norms) ----------------
__global__ __launch_bounds__(256) void prep_q(const float* __restrict__ q,
                                              unsigned short* __restrict__ qbf,
                                              float* __restrict__ qn) {
  const int b = blockIdx.x, tid = threadIdx.x;
  const float* row = q + (size_t)b * KD;
  float4 v0 = *(const float4*)(row + tid * 8);
  float4 v1 = *(const float4*)(row + tid * 8 + 4);
  float sq = v0.x * v0.x + v0.y * v0.y + v0.z * v0.z + v0.w * v0.w +
             v1.x * v1.x + v1.y * v1.y + v1.z * v1.z + v1.w * v1.w;
  uint4 o;
  o.x = pack_bf16(v0.x, v0.y);
  o.y = pack_bf16(v0.z, v0.w);
  o.z = pack_bf16(v1.x, v1.y);
  o.w = pack_bf16(v1.z, v1.w);
  *(uint4*)(qbf + (size_t)b * KD + tid * 8) = o;
  sq = wave_sum(sq);
  __shared__ float s4[4];
  if ((tid & 63) == 0) s4[tid >> 6] = sq;
  __syncthreads();
  if (tid == 0) qn[b] = sqrtf(s4[0] + s4[1] + s4[2] + s4[3]);
}

// ---------------- kernel 2: unified-FIFO pipelined bf16 MFMA GEMM ----------
// 256(M) x 64(N), BK=64, 512 threads (8 waves, M=32/wave), 1 block/CU.
// r5 post-mortem: vmcnt is FIFO, so ANY per-kt compiler-managed register
// global load (the A prefetch) drains the deep B prefetch every kt ->
// pipeline depth collapsed to ~1 kt regardless of structure. This version
// puts EVERY K-loop VMEM op into one pinned FIFO with counted waits:
//  * A: global_load_lds into a 3-slot LDS ring (32 KB/slot), issued 2 kt
//    ahead. No A register loads exist for the compiler to drain against.
//  * B: fp32 reg loads 3 kt ahead (2 banks), packed bf16 -> 3-slot ring.
//  * Per kt VMEM = [4 A-gloads][2 B-loads], SFENCE-pinned. Closing
//    "s_waitcnt vmcnt(8) lgkmcnt(0); s_barrier": the 8 newest ops are
//    exactly {B(t+2)x2, A(t+2)x4, B(t+3)x2}, so A(t+1) (needed next body)
//    is retired at the barrier in EVERY wave (gload_lds cross-wave
//    visibility), while 2 kt of A and 3 kt of B stay in flight. Tail
//    bodies peel with vmcnt(6)/vmcnt(0).
//  * Ring-3 audit: body t reads slot t%3, pack writes (t+1)%3, gloads
//    land in (t+2)%3 - pairwise disjoint; barrier/kt bounds skew to 0.
// Fragment maps, swizzles, MFMA and bsq order identical to r5 ->
// bit-identical scores (absmax 4.88e-4).
#define BSQ8(G0, G1)                                                     \
  (G0.x * G0.x + G0.y * G0.y + G0.z * G0.z + G0.w * G0.w + G1.x * G1.x + \
   G1.y * G1.y + G1.z * G1.z + G1.w * G1.w)

__global__ __launch_bounds__(512, 2) void gemm_scores(
    const float* __restrict__ bank, const unsigned short* __restrict__ qbf,
    const float* __restrict__ qn, float* __restrict__ out_scores,
    unsigned long long* __restrict__ bm) {
  __shared__ alignas(16) unsigned short As[3][MQ * BK];  // 3 x 32 KB ring
  __shared__ alignas(16) unsigned short Bs[3][BN * BK];  // 3 x 8 KB ring
  __shared__ float qn_s[MQ];
  __shared__ float bsq_s[512];
  __shared__ float bn_s[BN];

  const int tid = threadIdx.x;  // 0..511
  const int w = tid >> 6;       // 0..7
  const int lane = tid & 63;
  const int n0 = blockIdx.x * BN;

  if (tid < MQ) qn_s[tid] = qn[tid];

  f32x4 acc[2][4] = {};

  // B staging: thread t -> row t>>3, 8-float chunk (t&7)*8
  const int br = tid >> 3;
  const int bc = (tid & 7) * 8;
  const int be0 = bc ^ ((br & 7) * 8);  // swizzled bf16 slot (16B aligned)
  int brow = n0 + br;
  if (brow >= NB) brow = NB - 1;  // clamp; excluded at store
  const float* bsrc = bank + (size_t)brow * KD + bc;

  // A gload map: 4 ops/kt; op i covers rows i*64 + (tid>>3); source column
  // pre-swizzled so linear LDS dest (base + lane*16) yields swizzled tile.
  const int agr = tid >> 3;                        // 0..63 (= w*8 + lane>>3)
  const int acs = ((lane & 7) ^ (lane >> 3)) * 8;  // swizzled source col
  const unsigned short* asrc0 = qbf + (size_t)agr * KD + acs;
  const int adst = agr * BK + (lane & 7) * 8;  // elem offset within slot

  const int quad4 = lane >> 4;
  const int l15 = lane & 15;
  const int arow0 = (w * 32 + l15) * BK;
  const int arow1 = (w * 32 + 16 + l15) * BK;
  const int kxbase = (lane & 7) * 8;

  float bsq = 0.f;
  float4 gP0, gP1, gQ0, gQ1;

#define ISSUE_A(T_)                                                          \
  {                                                                          \
    unsigned short* dslot = &As[(T_) % 3][0];                                \
    const unsigned short* s0 = asrc0 + (size_t)(T_)*BK;                      \
    _Pragma("unroll") for (int i = 0; i < 4; ++i) {                          \
      __builtin_amdgcn_global_load_lds(                                      \
          (const __attribute__((address_space(1)))                           \
               unsigned int*)(s0 + (size_t)i * 64 * KD),                     \
          (__attribute__((address_space(3)))                                 \
               unsigned int*)(dslot + i * 64 * BK + adst),                   \
          16, 0, 0);                                                         \
    }                                                                        \
  }

#define LOAD_B(T_, G0_, G1_)                  \
  {                                           \
    const float* pp = bsrc + (size_t)(T_)*BK; \
    G0_ = *(const float4*)(pp);               \
    G1_ = *(const float4*)(pp + 4);           \
  }

#define PACK_B(T_, G0_, G1_)                    \
  {                                             \
    bsq += BSQ8(G0_, G1_);                      \
    uint4 pk;                                   \
    pk.x = pack_bf16(G0_.x, G0_.y);             \
    pk.y = pack_bf16(G0_.z, G0_.w);             \
    pk.z = pack_bf16(G1_.x, G1_.y);             \
    pk.w = pack_bf16(G1_.z, G1_.w);             \
    *(uint4*)&Bs[(T_) % 3][br * BK + be0] = pk; \
  }

#define COMPUTE(T_)                                                          \
  {                                                                          \
    const unsigned short* Asl = &As[(T_) % 3][0];                            \
    const unsigned short* Bsl = &Bs[(T_) % 3][0];                            \
    _Pragma("unroll") for (int s = 0; s < 2; ++s) {                          \
      const int kx = (s * 32 + quad4 * 8) ^ kxbase;                          \
      bf16x8 af0 = *(const bf16x8*)&Asl[arow0 + kx];                         \
      bf16x8 af1 = *(const bf16x8*)&Asl[arow1 + kx];                         \
      bf16x8 bfv[4];                                                         \
      _Pragma("unroll") for (int t = 0; t < 4; ++t) bfv[t] =                 \
          *(const bf16x8*)&Bsl[(t * 16 + l15) * BK + kx];                    \
      _Pragma("unroll") for (int tn = 0; tn < 4; ++tn) {                     \
        acc[0][tn] = __builtin_amdgcn_mfma_f32_16x16x32_bf16(                \
            af0, bfv[tn], acc[0][tn], 0, 0, 0);                              \
        acc[1][tn] = __builtin_amdgcn_mfma_f32_16x16x32_bf16(                \
            af1, bfv[tn], acc[1][tn], 0, 0, 0);                              \
      }                                                                      \
    }                                                                        \
  }

#define WAITBAR(VM_)                                                   \
  asm volatile("s_waitcnt vmcnt(" #VM_ ") lgkmcnt(0)" ::: "memory");   \
  __builtin_amdgcn_s_barrier();                                        \
  __builtin_amdgcn_sched_barrier(0);

#define BODY(T_, G0_, G1_, DOA_, DOB_, VM_)             \
  do {                                                  \
    if (DOA_) {                                         \
      ISSUE_A((T_) + 2);                                \
    }                                                   \
    SFENCE();                                           \
    COMPUTE(T_);                                        \
    SFENCE();                                           \
    PACK_B((T_) + 1, G0_, G1_);                         \
    SFENCE();                                           \
    if (DOB_) {                                         \
      LOAD_B((T_) + 3, G0_, G1_);                       \
      SFENCE();                                         \
    }                                                   \
    WAITBAR(VM_)                                        \
  } while (0)

  // ---- prologue: B(0) packed to Bs[0]; pinned FIFO fill:
  //      [A(0)x4][B(1)x2][A(1)x4][B(2)x2]; wait vmcnt(8) => A(0) retired.
  LOAD_B(0, gP0, gP1);
  PACK_B(0, gP0, gP1);
  SFENCE();
  ISSUE_A(0);
  SFENCE();
  LOAD_B(1, gQ0, gQ1);
  SFENCE();
  ISSUE_A(1);
  SFENCE();
  LOAD_B(2, gP0, gP1);
  SFENCE();
  WAITBAR(8)

  // ---- main loop: bodies 0..27; even packs odd tile (gQ), odd packs gP --
  for (int t = 0; t < KT - 4; t += 2) {
    BODY(t, gQ0, gQ1, 1, 1, 8);
    BODY(t + 1, gP0, gP1, 1, 1, 8);
  }
  // ---- peeled tail: bodies 28..31 ----
  BODY(KT - 4, gQ0, gQ1, 1, 1, 8);  // body 28: full
  BODY(KT - 3, gP0, gP1, 1, 0, 6);  // body 29: no B(32); ensure A(30)
  BODY(KT - 2, gQ0, gQ1, 0, 0, 0);  // body 30: no A(32); ensure A(31)
  COMPUTE(KT - 1);                  // body 31: compute only

#undef BODY
#undef WAITBAR
#undef COMPUTE
#undef PACK_B
#undef LOAD_B
#undef ISSUE_A

  // ---- b-norm reduce: 8 partials per row ----
  __syncthreads();
  bsq_s[tid] = bsq;
  __syncthreads();
  if (tid < BN) {
    float s = 0.f;
#pragma unroll
    for (int j = 0; j < 8; ++j) s += bsq_s[tid * 8 + j];
    bn_s[tid] = sqrtf(s);
  }
  __syncthreads();

  // ---- epilogue: scale, store, and per-(block,m) packed argmax ----
  const int quad = lane >> 4, nl = lane & 15;
#pragma unroll
  for (int tm = 0; tm < 2; ++tm) {
#pragma unroll
    for (int r = 0; r < 4; ++r) {
      const int m = w * 32 + tm * 16 + quad * 4 + r;
      const float qm = qn_s[m];
      unsigned long long best = 0ull;
#pragma unroll
      for (int tn = 0; tn < 4; ++tn) {
        const int gn = n0 + tn * 16 + nl;
        if (gn < NB) {
          const float sc =
              acc[tm][tn][r] / fmaxf(qm * bn_s[tn * 16 + nl], 1e-12f);
          out_scores[(size_t)m * NB + gn] = sc;
          const unsigned long long pk =
              ((unsigned long long)ordf(sc) << 32) | (unsigned int)gn;
          best = pk > best ? pk : best;
        }
      }
#pragma unroll
      for (int mask = 1; mask < 16; mask <<= 1) {
        const unsigned long long o = __shfl_xor(best, mask, 64);
        best = o > best ? o : best;
      }
      if (nl == 0) bm[(size_t)m * NBLK + blockIdx.x] = best;
    }
  }
}

// ---------------- kernel 3: argmax from block maxima + fp32 rescue ---------
// Global approx max from the 782 packed block maxima; blocks within
// delta=2e-3 of the max get their 64-score segment rescanned; candidates get
// exact fp32 rescoring (argmax of dot/bn is monotonic-equal to the reference
// score since qn is constant per row).
__global__ __launch_bounds__(256) void argmax_rescue(
    const unsigned long long* __restrict__ bm, const float* __restrict__ scores,
    const float* __restrict__ q, const float* __restrict__ bank,
    float* __restrict__ out_idx) {
  const int b = blockIdx.x, tid = threadIdx.x;
  const int w = tid >> 6, lane = tid & 63;
  const unsigned long long* rbm = bm + (size_t)b * NBLK;

  unsigned long long pmax = 0ull;
  for (int i = tid; i < NBLK; i += 256) {
    const unsigned long long v = rbm[i];
    pmax = v > pmax ? v : pmax;
  }
#pragma unroll
  for (int o = 32; o > 0; o >>= 1) {
    const unsigned long long v = __shfl_down(pmax, o, 64);
    pmax = v > pmax ? v : pmax;
  }
  __shared__ unsigned long long red[4];
  if (lane == 0) red[w] = pmax;
  __syncthreads();
  unsigned long long gmax = red[0];
#pragma unroll
  for (int i = 1; i < 4; ++i) gmax = red[i] > gmax ? red[i] : gmax;
  const float thr = deordf((unsigned int)(gmax >> 32)) - 2e-3f;

  __shared__ int cand[64];
  __shared__ int cnt;
  if (tid == 0) cnt = 0;
  __syncthreads();
  const float* srow = scores + (size_t)b * NB;
  for (int i = tid; i < NBLK; i += 256) {
    const float bmf = deordf((unsigned int)(rbm[i] >> 32));
    if (bmf >= thr) {  // rare (1-3 blocks): rescan its 64 scores
      const int base = i * BN;
      const int lim = min(BN, NB - base);
      for (int j = 0; j < lim; ++j) {
        if (srow[base + j] >= thr) {
          const int c = atomicAdd(&cnt, 1);
          if (c < 64) cand[c] = base + j;
        }
      }
    }
  }
  __syncthreads();
  const int nc = min(cnt, 64);

  __shared__ float dd[4], ss[4];
  float best = -1e30f;
  int bidx = 0x7fffffff;
  const float* qrow = q + (size_t)b * KD;
  for (int c = 0; c < nc; ++c) {
    const int idx = cand[c];
    const float* brow = bank + (size_t)idx * KD;
    float4 bv0 = *(const float4*)(brow + tid * 8);
    float4 bv1 = *(const float4*)(brow + tid * 8 + 4);
    float4 qv0 = *(const float4*)(qrow + tid * 8);
    float4 qv1 = *(const float4*)(qrow + tid * 8 + 4);
    float d = 0.f, s = 0.f;
    d = fmaf(qv0.x, bv0.x, d);
    s = fmaf(bv0.x, bv0.x, s);
    d = fmaf(qv0.y, bv0.y, d);
    s = fmaf(bv0.y, bv0.y, s);
    d = fmaf(qv0.z, bv0.z, d);
    s = fmaf(bv0.z, bv0.z, s);
    d = fmaf(qv0.w, bv0.w, d);
    s = fmaf(bv0.w, bv0.w, s);
    d = fmaf(qv1.x, bv1.x, d);
    s = fmaf(bv1.x, bv1.x, s);
    d = fmaf(qv1.y, bv1.y, d);
    s = fmaf(bv1.y, bv1.y, s);
    d = fmaf(qv1.z, bv1.z, d);
    s = fmaf(bv1.z, bv1.z, s);
    d = fmaf(qv1.w, bv1.w, d);
    s = fmaf(bv1.w, bv1.w, s);
    d = wave_sum(d);
    s = wave_sum(s);
    if (lane == 0) {
      dd[w] = d;
      ss[w] = s;
    }
    __syncthreads();
    const float dt = dd[0] + dd[1] + dd[2] + dd[3];
    const float st = ss[0] + ss[1] + ss[2] + ss[3];
    const float sc = dt / fmaxf(sqrtf(st), 1e-12f);
    if (sc > best || (sc == best && idx < bidx)) {
      best = sc;
      bidx = idx;
    }
    __syncthreads();
  }
  if (tid == 0) out_idx[b] = (float)bidx;
}

extern "C" void kernel_launch(void* const* d_in, const int* in_sizes, int n_in,
                              void* d_out, int out_size, void* d_ws,
                              size_t ws_size, hipStream_t stream) {
  const float* queries = (const float*)d_in[0];  // [256, 2048] fp32
  const float* bank = (const float*)d_in[1];     // [50000, 2048] fp32
  float* out = (float*)d_out;                    // [256 idx | 256*50000 scores]
  float* out_scores = out + MQ;

  char* ws = (char*)d_ws;
  unsigned short* qbf = (unsigned short*)ws;                 // 1 MB bf16 queries
  float* qn = (float*)(ws + (size_t)MQ * KD * 2);            // 1 KB q-norms
  unsigned long long* bm =
      (unsigned long long*)(ws + (size_t)MQ * KD * 2 + 2048);  // 1.6 MB maxima

  prep_q<<<MQ, 256, 0, stream>>>(queries, qbf, qn);
  gemm_scores<<<NBLK, 512, 0, stream>>>(bank, qbf, qn, out_scores, bm);
  argmax_rescue<<<MQ, 256, 0, stream>>>(bm, out_scores, queries, bank, out);
}